// Round 5
// baseline (33.269 us; speedup 1.0000x reference)
//
#include <hip/hip_runtime.h>

// DynamicMaskHead, fused single kernel (two-kernel split regressed: serialized
// compute vs store phases that the fused version overlaps across blocks).
//
// Grid: 2048 blocks = 128 instances x 16 row-slices = 8192 waves = exactly
// full chip residency (256 CU x 32 waves) -> VGPR must stay <= 64.
// Phase 1: 8 mask rows (pre-sigmoid) into 4 KB LDS; 2 px/thread (float2
//          feature loads), 2 row-iterations.
// Phase 2: 1 output col/thread x 12 rows; conflict-free LDS reads,
//          coalesced dword stores.

#define HH 192
#define WW 256
#define IH 96
#define IW 128
#define HW (HH * WW)

__device__ __forceinline__ float mlp_px(
    const float* __restrict__ p, const float* f, float relx, float rely)
{
    float a[8];
    #pragma unroll
    for (int k = 0; k < 8; ++k) {
        float acc = p[152 + k];
        acc = fmaf(p[k * 10 + 0], relx, acc);
        acc = fmaf(p[k * 10 + 1], rely, acc);
        #pragma unroll
        for (int c = 0; c < 8; ++c)
            acc = fmaf(p[k * 10 + 2 + c], f[c], acc);
        a[k] = fmaxf(acc, 0.0f);
    }
    float b[8];
    #pragma unroll
    for (int k = 0; k < 8; ++k) {
        float acc = p[160 + k];
        #pragma unroll
        for (int c = 0; c < 8; ++c)
            acc = fmaf(p[80 + k * 8 + c], a[c], acc);
        b[k] = fmaxf(acc, 0.0f);
    }
    float acc = p[168];
    #pragma unroll
    for (int c = 0; c < 8; ++c)
        acc = fmaf(p[144 + c], b[c], acc);
    return acc;
}

__global__ __launch_bounds__(256, 8) void dmh_kernel(
    const float* __restrict__ mf,      // (2,8,192,256)
    const float* __restrict__ params,  // (128,169)
    const float* __restrict__ locs,    // (128,2)
    const int*   __restrict__ im_inds, // (128)
    const int*   __restrict__ fpn,     // (128)
    const int*   __restrict__ stride_p,// (1)
    float*       __restrict__ out)     // (128,1,192,256)
{
    __shared__ float m[8 * IW];        // 4 KB mask-row stage

    const int bx   = blockIdx.x;
    const int inst = bx >> 4;
    const int q    = bx & 15;
    const int tid  = threadIdx.x;

    const int   s   = stride_p[0];     // 8
    const int   sh  = s >> 1;          // 4
    const float ix  = locs[2 * inst + 0];
    const float iy  = locs[2 * inst + 1];
    const float inv_soi = 1.0f / (float)(64 << fpn[inst]); // SOI are pow2
    const int   im  = im_inds[inst];

    // grid-cell selection (matches jnp: clip then true f32 divide, floor)
    const float nlx = ix * 0.125f;
    const float nly = iy * 0.125f;
    const int gx = (int)floorf(fminf(fmaxf(nlx, 0.0f), (float)(WW - 1)) / (float)(WW / 2));
    const int gy = (int)floorf(fminf(fmaxf(nly, 0.0f), (float)(HH - 1)) / (float)(HH / 2));

    const float* __restrict__ p = params + inst * 169;

    const int orow0 = q * 12;                                 // first output row
    const int ms    = (int)((float)orow0 * (95.0f / 191.0f)); // first mask row

    // ------- Phase 1: mask rows [ms, ms+7] into LDS; 2 px/thread x 2 -------
    {
        const int col2 = (tid & 63) * 2;       // 0..126
        const int r0   = tid >> 6;             // 0..3
        const float relx0 = (ix - (float)((gx * IW + col2) * s + sh)) * inv_soi;
        const float relx1 = relx0 - (float)s * inv_soi;
        const float* fcol = mf + (size_t)(im * 8) * HW + gx * IW + col2;

        #pragma unroll
        for (int rr = 0; rr < 2; ++rr) {
            const int r = r0 + rr * 4;         // 0..7
            int gr = ms + r; if (gr > IH - 1) gr = IH - 1;   // clamp (row unused)
            const int h = gy * IH + gr;
            const float rely = (iy - (float)(h * s + sh)) * inv_soi;

            const float* fbase = fcol + (size_t)h * WW;
            float f0[8], f1[8];
            #pragma unroll
            for (int c = 0; c < 8; ++c) {
                const float2 t = *(const float2*)(fbase + (size_t)c * HW);
                f0[c] = t.x; f1[c] = t.y;
            }

            float2 res;
            res.x = mlp_px(p, f0, relx0, rely);
            res.y = mlp_px(p, f1, relx1, rely);
            *(float2*)&m[r * IW + col2] = res;
        }
    }
    __syncthreads();

    // ------- Phase 2: one output column/thread, 12 rows, sigmoid ------------
    {
        const int ocol = tid;                                  // 0..255
        const float wpos = (float)ocol * (127.0f / 255.0f);
        int wlo = (int)wpos; if (wlo > IW - 2) wlo = IW - 2;
        const float fw = wpos - (float)wlo;

        float* op = out + (size_t)inst * HW + (size_t)orow0 * WW + ocol;

        #pragma unroll
        for (int r = 0; r < 12; ++r) {
            const float hpos = (float)(orow0 + r) * (95.0f / 191.0f);
            int hlo = (int)hpos; if (hlo > IH - 2) hlo = IH - 2;
            const float fh = hpos - (float)hlo;
            const int rl = hlo - ms;                           // 0..6 (uniform)

            const float* mp = &m[rl * IW + wlo];
            const float v00 = mp[0];
            const float v01 = mp[1];
            const float v10 = mp[IW];
            const float v11 = mp[IW + 1];

            const float top = fmaf(fw, v01 - v00, v00);
            const float bot = fmaf(fw, v11 - v10, v10);
            const float val = fmaf(fh, bot - top, top);

            op[(size_t)r * WW] = 1.0f / (1.0f + __expf(-val));
        }
    }
}

extern "C" void kernel_launch(void* const* d_in, const int* in_sizes, int n_in,
                              void* d_out, int out_size, void* d_ws, size_t ws_size,
                              hipStream_t stream) {
    const float* mf       = (const float*)d_in[0];
    const float* params   = (const float*)d_in[1];
    const float* locs     = (const float*)d_in[2];
    const int*   im_inds  = (const int*)d_in[3];
    const int*   fpn      = (const int*)d_in[4];
    const int*   stride_p = (const int*)d_in[5];
    float*       out      = (float*)d_out;

    dmh_kernel<<<dim3(2048), dim3(256), 0, stream>>>(
        mf, params, locs, im_inds, fpn, stride_p, out);
}

// Round 6
// 20.969 us; speedup vs baseline: 1.5866x; 1.5866x over previous
//
#include <hip/hip_runtime.h>

// DynamicMaskHead fused kernel — r3 structure (proven 20.6us) with ONE change:
// phase-1 MLP computes the 4 pixels JOINTLY, k-outer, so each wave-uniform
// weight p[*] is fetched once (not 4x) and feeds 4 independent FMAs.
//
// Grid: 2048 blocks = 128 instances x 16 row-slices. 256 threads/block.
// Phase 1: 8 mask rows into 4KB LDS; thread = (row, 4 adjacent cols),
//          8x float4 feature loads, joint-4px MLP.
// Phase 2: thread = 1 output col x 12 rows; conflict-free LDS reads,
//          coalesced dword stores. (identical to r3)

#define HH 192
#define WW 256
#define IH 96
#define IW 128
#define HW (HH * WW)

__device__ __forceinline__ float4 fma4s(float s, float4 x, float4 acc) {
    acc.x = fmaf(s, x.x, acc.x);
    acc.y = fmaf(s, x.y, acc.y);
    acc.z = fmaf(s, x.z, acc.z);
    acc.w = fmaf(s, x.w, acc.w);
    return acc;
}
__device__ __forceinline__ float4 max4z(float4 v) {
    v.x = fmaxf(v.x, 0.0f); v.y = fmaxf(v.y, 0.0f);
    v.z = fmaxf(v.z, 0.0f); v.w = fmaxf(v.w, 0.0f);
    return v;
}
__device__ __forceinline__ float4 bcast4(float s) {
    return make_float4(s, s, s, s);
}

__global__ __launch_bounds__(256, 4) void dmh_kernel(
    const float* __restrict__ mf,      // (2,8,192,256)
    const float* __restrict__ params,  // (128,169)
    const float* __restrict__ locs,    // (128,2)
    const int*   __restrict__ im_inds, // (128)
    const int*   __restrict__ fpn,     // (128)
    const int*   __restrict__ stride_p,// (1)
    float*       __restrict__ out)     // (128,1,192,256)
{
    __shared__ float m[8 * IW];        // 4 KB mask-row stage

    const int bx   = blockIdx.x;
    const int inst = bx >> 4;
    const int q    = bx & 15;
    const int tid  = threadIdx.x;

    const int   s   = stride_p[0];     // 8
    const int   sh  = s >> 1;          // 4
    const float ix  = locs[2 * inst + 0];
    const float iy  = locs[2 * inst + 1];
    const float inv_soi = 1.0f / (float)(64 << fpn[inst]); // SOI are pow2
    const int   im  = im_inds[inst];

    // grid-cell selection (matches jnp: clip then true f32 divide, floor)
    const float nlx = ix * 0.125f;
    const float nly = iy * 0.125f;
    const int gx = (int)floorf(fminf(fmaxf(nlx, 0.0f), (float)(WW - 1)) / (float)(WW / 2));
    const int gy = (int)floorf(fminf(fmaxf(nly, 0.0f), (float)(HH - 1)) / (float)(HH / 2));

    const float* __restrict__ p = params + inst * 169;

    const int orow0 = q * 12;                                 // first output row
    const int ms    = (int)((float)orow0 * (95.0f / 191.0f)); // first mask row

    // ------- Phase 1: mask rows [ms, ms+7] into LDS; joint 4 px/thread -----
    {
        const int col4 = (tid & 31) * 4;       // 0,4,...,124
        const int r    = tid >> 5;             // 0..7 (one mask row/thread)
        int gr = ms + r; if (gr > IH - 1) gr = IH - 1;   // clamp (last slice)
        const int h = gy * IH + gr;
        const float rely = (iy - (float)(h * s + sh)) * inv_soi;

        const float* fbase = mf + (size_t)(im * 8) * HW + (size_t)h * WW
                             + gx * IW + col4;
        float4 f[8];
        #pragma unroll
        for (int c = 0; c < 8; ++c)
            f[c] = *(const float4*)(fbase + (size_t)c * HW);

        // relx for the 4 adjacent pixels (step -s*inv_soi per column)
        const float relx0 = (ix - (float)((gx * IW + col4) * s + sh)) * inv_soi;
        const float dstep = (float)s * inv_soi;
        const float4 relx = make_float4(relx0, relx0 - dstep,
                                        relx0 - 2.0f * dstep, relx0 - 3.0f * dstep);
        const float4 rely4 = bcast4(rely);

        // layer 0: 10 -> 8, relu  (k-outer: each weight fetched once, x4 ILP)
        float4 a[8];
        #pragma unroll
        for (int k = 0; k < 8; ++k) {
            float4 acc = bcast4(p[152 + k]);
            acc = fma4s(p[k * 10 + 0], relx, acc);
            acc = fma4s(p[k * 10 + 1], rely4, acc);
            #pragma unroll
            for (int c = 0; c < 8; ++c)
                acc = fma4s(p[k * 10 + 2 + c], f[c], acc);
            a[k] = max4z(acc);
        }
        // layer 1: 8 -> 8, relu
        float4 b[8];
        #pragma unroll
        for (int k = 0; k < 8; ++k) {
            float4 acc = bcast4(p[160 + k]);
            #pragma unroll
            for (int c = 0; c < 8; ++c)
                acc = fma4s(p[80 + k * 8 + c], a[c], acc);
            b[k] = max4z(acc);
        }
        // layer 2: 8 -> 1
        float4 res = bcast4(p[168]);
        #pragma unroll
        for (int c = 0; c < 8; ++c)
            res = fma4s(p[144 + c], b[c], res);

        *(float4*)&m[r * IW + col4] = res;
    }
    __syncthreads();

    // ------- Phase 2: one output column/thread, 12 rows, sigmoid ------------
    {
        const int ocol = tid;                                  // 0..255
        const float wpos = (float)ocol * (127.0f / 255.0f);
        int wlo = (int)wpos; if (wlo > IW - 2) wlo = IW - 2;
        const float fw = wpos - (float)wlo;

        float* op = out + (size_t)inst * HW + (size_t)orow0 * WW + ocol;

        #pragma unroll
        for (int r = 0; r < 12; ++r) {
            const float hpos = (float)(orow0 + r) * (95.0f / 191.0f);
            int hlo = (int)hpos; if (hlo > IH - 2) hlo = IH - 2;
            const float fh = hpos - (float)hlo;
            const int rl = hlo - ms;                           // 0..6 (uniform)

            const float* mp = &m[rl * IW + wlo];
            const float v00 = mp[0];
            const float v01 = mp[1];
            const float v10 = mp[IW];
            const float v11 = mp[IW + 1];

            const float top = fmaf(fw, v01 - v00, v00);
            const float bot = fmaf(fw, v11 - v10, v10);
            const float val = fmaf(fh, bot - top, top);

            op[(size_t)r * WW] = 1.0f / (1.0f + __expf(-val));
        }
    }
}

extern "C" void kernel_launch(void* const* d_in, const int* in_sizes, int n_in,
                              void* d_out, int out_size, void* d_ws, size_t ws_size,
                              hipStream_t stream) {
    const float* mf       = (const float*)d_in[0];
    const float* params   = (const float*)d_in[1];
    const float* locs     = (const float*)d_in[2];
    const int*   im_inds  = (const int*)d_in[3];
    const int*   fpn      = (const int*)d_in[4];
    const int*   stride_p = (const int*)d_in[5];
    float*       out      = (float*)d_out;

    dmh_kernel<<<dim3(2048), dim3(256), 0, stream>>>(
        mf, params, locs, im_inds, fpn, stride_p, out);
}